// Round 2
// baseline (690.433 us; speedup 1.0000x reference)
//
#include <hip/hip_runtime.h>

#define EMBED 1024
#define BATCH 4
#define SEQ   4096
#define ROWS  (BATCH*SEQ)   // 16384
#define CAP   128           // candidate slots per row (r3-r12 proven)
#define TSCAN_U 1600.0f     // scan margin, unscaled (50 scaled) — r12-proven passing
#define TRES  75.0f         // rescore margin, scaled logits (proven)

typedef __attribute__((ext_vector_type(8))) short bf16x8;
typedef __attribute__((ext_vector_type(4))) float f32x4;

static __device__ __forceinline__ unsigned short f2bf(float x) {
    unsigned u = __float_as_uint(x);
    u = (u + 0x7fffu + ((u >> 16) & 1u)) >> 16;
    return (unsigned short)u;
}
static __device__ __forceinline__ float bf2f(unsigned short h) {
    return __uint_as_float(((unsigned)h) << 16);
}
static __device__ __forceinline__ void split2(float x, unsigned short& hi, unsigned short& lo) {
    hi = f2bf(x);
    lo = f2bf(x - bf2f(hi));
}

// ---- async global->LDS staging, 128x32-short tile, 4-segment swizzle (r3-proven, 0 conflicts) ----
static __device__ __forceinline__ void stage_tile(unsigned short (*lds)[32],
                                                  const unsigned short* gbase,
                                                  int wave, int lane) {
#pragma unroll
    for (int c = 0; c < 2; c++) {
        int L = wave * 128 + c * 64 + lane;   // linear segment index 0..511
        int r = L >> 2, s = L & 3;
        int g = (s - (r >> 1)) & 3;
        __builtin_amdgcn_global_load_lds(
            (const __attribute__((address_space(1))) unsigned int*)(gbase + (size_t)r * EMBED + g * 8),
            (__attribute__((address_space(3))) unsigned int*)(&lds[r][s * 8]),
            16, 0, 0);
    }
}
static __device__ __forceinline__ bf16x8 read_frag(const unsigned short (*lds)[32], int r, int kq) {
    int s = ((kq >> 3) + (r >> 1)) & 3;
    return *(const bf16x8*)&lds[r][s * 8];
}

// ---------------- prep: wv_bar[i] = mean_d Wv[i][d] ----------------
__global__ void k_wvbar(const float* __restrict__ Wv, float* __restrict__ wvbar) {
    int r = blockIdx.x, t = threadIdx.x;
    float s = 0.f;
    for (int c = t; c < EMBED; c += 256) s += Wv[(size_t)r * EMBED + c];
    for (int d = 1; d < 64; d <<= 1) s += __shfl_xor(s, d);
    __shared__ float ws_[4];
    if ((t & 63) == 0) ws_[t >> 6] = s;
    __syncthreads();
    if (t == 0) wvbar[r] = (ws_[0] + ws_[1] + ws_[2] + ws_[3]) * (1.0f / EMBED);
}

// ---------------- prep: row split + vmean + cnt zeroing (fused, one X read) ----------------
__global__ __launch_bounds__(256) void k_xsplit_vmean(
    const float* __restrict__ X, const float* __restrict__ wvbar,
    unsigned short* __restrict__ Xhi, unsigned short* __restrict__ Xlo,
    float* __restrict__ vmean, int* __restrict__ cnt) {
    int row = blockIdx.x, t = threadIdx.x;
    float4 x4 = *(const float4*)(X + (size_t)row * EMBED + t * 4);
    float4 w4 = *(const float4*)(wvbar + t * 4);
    ushort4 h, l;
    split2(x4.x, h.x, l.x); split2(x4.y, h.y, l.y);
    split2(x4.z, h.z, l.z); split2(x4.w, h.w, l.w);
    *(ushort4*)(Xhi + (size_t)row * EMBED + t * 4) = h;
    *(ushort4*)(Xlo + (size_t)row * EMBED + t * 4) = l;
    float s = x4.x * w4.x + x4.y * w4.y + x4.z * w4.z + x4.w * w4.w;
    for (int d = 1; d < 64; d <<= 1) s += __shfl_xor(s, d);
    __shared__ float ws_[4];
    if ((t & 63) == 0) ws_[t >> 6] = s;
    __syncthreads();
    if (t == 0) { vmean[row] = ws_[0] + ws_[1] + ws_[2] + ws_[3]; cnt[row] = 0; }
}

// ---------------- split-bf16 GEMM: C[row][col] = sum_k A[row][k]*B[col][k] ----------------
__global__ __launch_bounds__(256) void k_gemm3(
    const unsigned short* __restrict__ Ahi, const unsigned short* __restrict__ Alo,
    const unsigned short* __restrict__ BThi, const unsigned short* __restrict__ BTlo,
    unsigned short* __restrict__ Chi, unsigned short* __restrict__ Clo) {
    __shared__ unsigned short Ah[128][32], Al[128][32], Bh[128][32], Bl[128][32];
    int bx = blockIdx.x;
    int bm = bx >> 3, bn = bx & 7;   // bn == XCD id under round-robin: B-tiles L2-local
    int tid = threadIdx.x, wave = tid >> 6, lane = tid & 63;
    int wm = (wave >> 1) * 64, wn = (wave & 1) * 64;
    int mrow = lane & 15, kq = (lane >> 4) * 8;

    f32x4 zero = {0.f, 0.f, 0.f, 0.f};
    f32x4 acc[4][4];
    for (int a = 0; a < 4; a++) for (int b = 0; b < 4; b++) acc[a][b] = zero;

    const unsigned short* Abase_h = Ahi + (size_t)(bm * 128) * EMBED;
    const unsigned short* Abase_l = Alo + (size_t)(bm * 128) * EMBED;
    const unsigned short* Bbase_h = BThi + (size_t)(bn * 128) * EMBED;
    const unsigned short* Bbase_l = BTlo + (size_t)(bn * 128) * EMBED;

    for (int k0 = 0; k0 < EMBED; k0 += 32) {
        __syncthreads();
        stage_tile(Ah, Abase_h + k0, wave, lane);
        stage_tile(Al, Abase_l + k0, wave, lane);
        stage_tile(Bh, Bbase_h + k0, wave, lane);
        stage_tile(Bl, Bbase_l + k0, wave, lane);
        __syncthreads();
        bf16x8 ah[4], al[4], bh[4], bl[4];
#pragma unroll
        for (int t = 0; t < 4; t++) {
            ah[t] = read_frag(Ah, wm + t * 16 + mrow, kq);
            al[t] = read_frag(Al, wm + t * 16 + mrow, kq);
            bh[t] = read_frag(Bh, wn + t * 16 + mrow, kq);
            bl[t] = read_frag(Bl, wn + t * 16 + mrow, kq);
        }
#pragma unroll
        for (int mt = 0; mt < 4; mt++)
#pragma unroll
            for (int nt = 0; nt < 4; nt++) {
                acc[mt][nt] = __builtin_amdgcn_mfma_f32_16x16x32_bf16(ah[mt], bh[nt], acc[mt][nt], 0, 0, 0);
                acc[mt][nt] = __builtin_amdgcn_mfma_f32_16x16x32_bf16(ah[mt], bl[nt], acc[mt][nt], 0, 0, 0);
                acc[mt][nt] = __builtin_amdgcn_mfma_f32_16x16x32_bf16(al[mt], bh[nt], acc[mt][nt], 0, 0, 0);
            }
    }
#pragma unroll
    for (int mt = 0; mt < 4; mt++)
#pragma unroll
        for (int nt = 0; nt < 4; nt++)
#pragma unroll
            for (int i = 0; i < 4; i++) {
                int row = bm * 128 + wm + mt * 16 + (lane >> 4) * 4 + i;
                int col = bn * 128 + wn + nt * 16 + (lane & 15);
                unsigned short h, l; split2(acc[mt][nt][i], h, l);
                Chi[(size_t)row * EMBED + col] = h;
                Clo[(size_t)row * EMBED + col] = l;
            }
}

// ---------------- scan: 128q x 256k tile; each wave owns 64q x 128k ----------------
// r13 post-mortem: 2-buffer dbuf with per-step vmcnt(0) drain = perfect null (m218's
// "8-phase-with-drain0 == 1-phase" law). The gain of pipelining IS the counted vmcnt:
// loads must stay in flight ACROSS the barrier. This version: 3-buffer rotation, step i
// computes buf i%3 / stages buf (i+2)%3, and each barrier waits vmcnt(6) — draining only
// the 6 loads issued ONE FULL STEP earlier (~1500+cy cover) while the current step's 6
// ride through. Buffer-reuse safety: buf (i+2)%3 was step i-1's compute buffer, whose
// ds_reads drained (lgkmcnt 0) before step i-1's barrier. setprio(1) wraps the MFMA
// cluster (waves now have genuine load-issuing vs MFMA role diversity — T5 gate).
// Staging addresses hoisted: per-lane global/LDS offsets are k-invariant; only two
// running pointers advance per step.
static __device__ __forceinline__ void stage6(
    unsigned short (*Ts)[32], unsigned short (*Ks)[32],
    const unsigned short* Tk, const unsigned short* Xk,
    const int* tg, const int* tl, const int* kg, const int* kl) {
#pragma unroll
    for (int c = 0; c < 2; c++)
        __builtin_amdgcn_global_load_lds(
            (const __attribute__((address_space(1))) unsigned int*)(Tk + tg[c]),
            (__attribute__((address_space(3))) unsigned int*)((unsigned short*)Ts + tl[c]),
            16, 0, 0);
#pragma unroll
    for (int c = 0; c < 4; c++)
        __builtin_amdgcn_global_load_lds(
            (const __attribute__((address_space(1))) unsigned int*)(Xk + kg[c]),
            (__attribute__((address_space(3))) unsigned int*)((unsigned short*)Ks + kl[c]),
            16, 0, 0);
}

// MODE: 0 = stage + vmcnt(6) + barrier (steady state)
//       1 = no stage + vmcnt(0) + barrier (step 30)
//       2 = no stage, no wait/barrier (step 31)
template<int MODE>
static __device__ __forceinline__ void scan_step3(
    const unsigned short (*Tc)[32], const unsigned short (*Kc)[32],
    unsigned short (*Ts)[32], unsigned short (*Ks)[32],
    const unsigned short* Tk, const unsigned short* Xk,
    const int* tg, const int* tl, const int* kg, const int* kl,
    int wq, int wk, int mrow, int kqo, f32x4 (&acc)[4][8]) {
    if (MODE == 0) stage6(Ts, Ks, Tk, Xk, tg, tl, kg, kl);
    bf16x8 ah[4];
#pragma unroll
    for (int mt = 0; mt < 4; mt++)
        ah[mt] = read_frag(Tc, wq + mt * 16 + mrow, kqo);
    __builtin_amdgcn_s_setprio(1);
#pragma unroll
    for (int nt = 0; nt < 8; nt++) {
        bf16x8 bh = read_frag(Kc, wk + nt * 16 + mrow, kqo);
#pragma unroll
        for (int mt = 0; mt < 4; mt++)
            acc[mt][nt] = __builtin_amdgcn_mfma_f32_16x16x32_bf16(ah[mt], bh, acc[mt][nt], 0, 0, 0);
    }
    __builtin_amdgcn_s_setprio(0);
    if (MODE == 0) {
        asm volatile("s_waitcnt vmcnt(6) lgkmcnt(0)" ::: "memory");
        __builtin_amdgcn_s_barrier();
        asm volatile("" ::: "memory");
    } else if (MODE == 1) {
        asm volatile("s_waitcnt vmcnt(0) lgkmcnt(0)" ::: "memory");
        __builtin_amdgcn_s_barrier();
        asm volatile("" ::: "memory");
    }
}

__global__ __launch_bounds__(256, 3) void k_scan(
    const unsigned short* __restrict__ Thi, const unsigned short* __restrict__ Xhi,
    int* __restrict__ cnt, int2* __restrict__ cand) {
    __shared__ unsigned short Th0[128][32], Th1[128][32], Th2[128][32];
    __shared__ unsigned short Kh0[256][32], Kh1[256][32], Kh2[256][32];   // 72 KB total
    // XCD-aware swizzle: XCD = bid%8 under round-robin; each XCD gets 2 fixed 256-key
    // super-tiles -> its X working set stays L2-warm.
    int bid = blockIdx.x;            // 0..2047
    int x  = bid & 7;                // XCD id
    int i  = bid >> 3;               // 0..255
    int qb = i & 31;
    int kb2 = x * 2 + ((i >> 5) & 1);
    int b  = i >> 6;
    int tid = threadIdx.x, wave = tid >> 6, lane = tid & 63;
    int wq = (wave >> 1) * 64;       // q offset of this wave
    int wk = (wave & 1) * 128;       // k offset: each wave covers one full 128-key tile
    int mrow = lane & 15, kq = (lane >> 4) * 8;
    size_t qrow0 = (size_t)b * SEQ + (size_t)qb * 128;
    size_t krow0 = (size_t)b * SEQ + (size_t)kb2 * 256;

    const unsigned short* Tbase = Thi + qrow0 * EMBED;
    const unsigned short* Xbase = Xhi + krow0 * EMBED;

    // k-invariant per-lane staging offsets (global elem off, LDS short off)
    int tg[2], tl[2], kg[4], kl[4];
#pragma unroll
    for (int c = 0; c < 2; c++) {
        int L = wave * 128 + c * 64 + lane, r = L >> 2, s = L & 3, g = (s - (r >> 1)) & 3;
        tg[c] = r * EMBED + g * 8; tl[c] = r * 32 + s * 8;
    }
#pragma unroll
    for (int c = 0; c < 4; c++) {
        int L = wave * 256 + c * 64 + lane, r = L >> 2, s = L & 3, g = (s - (r >> 1)) & 3;
        kg[c] = r * EMBED + g * 8; kl[c] = r * 32 + s * 8;
    }

    f32x4 zero = {0.f, 0.f, 0.f, 0.f};
    f32x4 acc[4][8];
    for (int a = 0; a < 4; a++) for (int c = 0; c < 8; c++) acc[a][c] = zero;

    // prologue: stage k=0 -> buf0, k=32 -> buf1; wait only for buf0's 6 (leave buf1's riding)
    stage6(Th0, Kh0, Tbase,      Xbase,      tg, tl, kg, kl);
    stage6(Th1, Kh1, Tbase + 32, Xbase + 32, tg, tl, kg, kl);
    asm volatile("s_waitcnt vmcnt(6)" ::: "memory");
    __builtin_amdgcn_s_barrier();
    asm volatile("" ::: "memory");

    const unsigned short* Tk = Tbase + 64;   // next k to stage
    const unsigned short* Xk = Xbase + 64;
    // steps 0..29: 10 iterations x 3 steps, static buffer rotation
    for (int it = 0; it < 10; it++) {
        scan_step3<0>(Th0, Kh0, Th2, Kh2, Tk, Xk, tg, tl, kg, kl, wq, wk, mrow, kq, acc);
        Tk += 32; Xk += 32;
        scan_step3<0>(Th1, Kh1, Th0, Kh0, Tk, Xk, tg, tl, kg, kl, wq, wk, mrow, kq, acc);
        Tk += 32; Xk += 32;
        scan_step3<0>(Th2, Kh2, Th1, Kh1, Tk, Xk, tg, tl, kg, kl, wq, wk, mrow, kq, acc);
        Tk += 32; Xk += 32;
    }
    // step 30: compute buf0 (k=960), no stage, drain last loads (k=992 -> buf1)
    scan_step3<1>(Th0, Kh0, Th0, Kh0, Tk, Xk, tg, tl, kg, kl, wq, wk, mrow, kq, acc);
    // step 31: compute buf1 (k=992), no stage, no barrier
    scan_step3<2>(Th1, Kh1, Th1, Kh1, Tk, Xk, tg, tl, kg, kl, wq, wk, mrow, kq, acc);

    // ---- epilogue: per-row max over this wave's 128 keys (intra-wave; no LDS, no barrier) ----
#pragma unroll
    for (int mt = 0; mt < 4; mt++)
#pragma unroll
        for (int i2 = 0; i2 < 4; i2++) {
            float v = -INFINITY;
#pragma unroll
            for (int nt = 0; nt < 8; nt++) v = fmaxf(v, acc[mt][nt][i2]);
#pragma unroll
            for (int d = 1; d < 16; d <<= 1) v = fmaxf(v, __shfl_xor(v, d));
            float th = v - TSCAN_U;
            int grow = (int)qrow0 + wq + mt * 16 + (lane >> 4) * 4 + i2;
#pragma unroll
            for (int nt = 0; nt < 8; nt++) {
                float s = acc[mt][nt][i2];
                if (s >= th) {
                    int gcol = (int)krow0 + wk + nt * 16 + (lane & 15);
                    int idx = atomicAdd(&cnt[grow], 1);
                    if (idx < CAP)
                        cand[(size_t)grow * CAP + idx] = make_int2(gcol, __float_as_int(s * 0.03125f));
                }
            }
        }
}

// ---------------- rescore: 4 rows per block, one wave per row, barrier-free ----------------
__global__ __launch_bounds__(256) void k_rescore(
    const unsigned short* __restrict__ Thi, const unsigned short* __restrict__ Tlo,
    const float* __restrict__ X, const float* __restrict__ vmean,
    const int* __restrict__ cnt, const int2* __restrict__ cand,
    float* __restrict__ out) {
    int wave = threadIdx.x >> 6, lane = threadIdx.x & 63;
    int row = blockIdx.x * 4 + wave;
    int c = cnt[row]; if (c > CAP) c = CAP;
    const int2* cl = cand + (size_t)row * CAP;

    float smax = -INFINITY;
    for (int j = lane; j < c; j += 64) smax = fmaxf(smax, __int_as_float(cl[j].y));
    for (int d = 1; d < 64; d <<= 1) smax = fmaxf(smax, __shfl_xor(smax, d));
    float th = smax - TRES;

    float q[16];
    {
        const unsigned short* qh = Thi + (size_t)row * EMBED + lane * 16;
        const unsigned short* ql = Tlo + (size_t)row * EMBED + lane * 16;
        bf16x8 h0 = *(const bf16x8*)qh, h1 = *(const bf16x8*)(qh + 8);
        bf16x8 l0 = *(const bf16x8*)ql, l1 = *(const bf16x8*)(ql + 8);
#pragma unroll
        for (int i = 0; i < 8; i++) {
            q[i]     = bf2f((unsigned short)h0[i]) + bf2f((unsigned short)l0[i]);
            q[i + 8] = bf2f((unsigned short)h1[i]) + bf2f((unsigned short)l1[i]);
        }
    }

    __shared__ int   sm_[4][CAP];
    __shared__ float sl_[4][CAP];
    __shared__ int   ns_[4];
    if (lane == 0) ns_[wave] = 0;
    for (int j = lane; j < c; j += 64) {
        int2 p = cl[j];
        if (__int_as_float(p.y) >= th) {
            int idx = atomicAdd(&ns_[wave], 1);
            sm_[wave][idx] = p.x;
        }
    }
    int ns = ns_[wave];
    for (int t = 0; t < ns; t++) {
        int m = sm_[wave][t];
        const float* xr = X + (size_t)m * EMBED + lane * 16;
        float4 a0 = *(const float4*)(xr);
        float4 a1 = *(const float4*)(xr + 4);
        float4 a2 = *(const float4*)(xr + 8);
        float4 a3 = *(const float4*)(xr + 12);
        float dp = q[0]*a0.x + q[1]*a0.y + q[2]*a0.z + q[3]*a0.w
                 + q[4]*a1.x + q[5]*a1.y + q[6]*a1.z + q[7]*a1.w
                 + q[8]*a2.x + q[9]*a2.y + q[10]*a2.z + q[11]*a2.w
                 + q[12]*a3.x + q[13]*a3.y + q[14]*a3.z + q[15]*a3.w;
        for (int d = 1; d < 64; d <<= 1) dp += __shfl_xor(dp, d);
        if (lane == 0) sl_[wave][t] = dp * 0.03125f;
    }
    if (lane == 0) {
        float lm = -INFINITY;
        for (int t = 0; t < ns; t++) lm = fmaxf(lm, sl_[wave][t]);
        float den = 0.f, num = 0.f;
        for (int t = 0; t < ns; t++) {
            float e = __expf(sl_[wave][t] - lm);
            den += e;
            num += e * vmean[sm_[wave][t]];
        }
        out[row] = num / den;
    }
}

extern "C" void kernel_launch(void* const* d_in, const int* in_sizes, int n_in,
                              void* d_out, int out_size, void* d_ws, size_t ws_size,
                              hipStream_t stream) {
    const float* X  = (const float*)d_in[0];
    const float* Wq = (const float*)d_in[1];
    const float* Wk = (const float*)d_in[2];
    const float* Wv = (const float*)d_in[3];
    float* out = (float*)d_out;

    char* p = (char*)d_ws;
    auto alloc = [&](size_t bytes) -> void* {
        void* q = (void*)p;
        p += (bytes + 255) & ~(size_t)255;
        return q;
    };
    unsigned short* Wqhi = (unsigned short*)alloc((size_t)EMBED * EMBED * 2);
    unsigned short* Wqlo = (unsigned short*)alloc((size_t)EMBED * EMBED * 2);
    unsigned short* Wkhi = (unsigned short*)alloc((size_t)EMBED * EMBED * 2);
    unsigned short* Wklo = (unsigned short*)alloc((size_t)EMBED * EMBED * 2);
    unsigned short* MThi = (unsigned short*)alloc((size_t)EMBED * EMBED * 2);
    unsigned short* MTlo = (unsigned short*)alloc((size_t)EMBED * EMBED * 2);
    unsigned short* Xhi  = (unsigned short*)alloc((size_t)ROWS * EMBED * 2);
    unsigned short* Xlo  = (unsigned short*)alloc((size_t)ROWS * EMBED * 2);
    unsigned short* Thi  = (unsigned short*)alloc((size_t)ROWS * EMBED * 2);
    unsigned short* Tlo  = (unsigned short*)alloc((size_t)ROWS * EMBED * 2);
    float* wvbar = (float*)alloc(EMBED * 4);
    float* vmean = (float*)alloc((size_t)ROWS * 4);
    int*   cnt   = (int*)alloc((size_t)ROWS * 4);
    int2*  cand  = (int2*)alloc((size_t)ROWS * CAP * 8);

    k_wvbar<<<EMBED, 256, 0, stream>>>(Wv, wvbar);
    // Row splits of the ORIGINAL Wq/Wk (M contraction is over the contiguous output dim).
    // vmean/cnt args are scratch here (rows 0..1023; real run below overwrites all rows).
    k_xsplit_vmean<<<EMBED, 256, 0, stream>>>(Wq, wvbar, Wqhi, Wqlo, vmean, cnt);
    k_xsplit_vmean<<<EMBED, 256, 0, stream>>>(Wk, wvbar, Wkhi, Wklo, vmean, cnt);
    // M^T[b][a] = sum_n Wk[b][n]*Wq[a][n]
    k_gemm3<<<64, 256, 0, stream>>>(Wkhi, Wklo, Wqhi, Wqlo, MThi, MTlo);
    k_xsplit_vmean<<<ROWS, 256, 0, stream>>>(X, wvbar, Xhi, Xlo, vmean, cnt);  // real vmean + cnt=0
    k_gemm3<<<1024, 256, 0, stream>>>(Xhi, Xlo, MThi, MTlo, Thi, Tlo);         // T = X.M
    k_scan<<<2048, 256, 0, stream>>>(Thi, Xhi, cnt, cand);
    k_rescore<<<ROWS / 4, 256, 0, stream>>>(Thi, Tlo, X, vmean, cnt, cand, out);
}

// Round 3
// 506.155 us; speedup vs baseline: 1.3641x; 1.3641x over previous
//
#include <hip/hip_runtime.h>

#define EMBED 1024
#define BATCH 4
#define SEQ   4096
#define ROWS  (BATCH*SEQ)   // 16384
#define CAP   128           // candidate slots per row (r3-r12 proven)
#define TSCAN_U 1600.0f     // scan margin, unscaled (50 scaled) — r12-proven passing
#define TRES  75.0f         // rescore margin, scaled logits (proven)

typedef __attribute__((ext_vector_type(8))) short bf16x8;
typedef __attribute__((ext_vector_type(4))) float f32x4;

static __device__ __forceinline__ unsigned short f2bf(float x) {
    unsigned u = __float_as_uint(x);
    u = (u + 0x7fffu + ((u >> 16) & 1u)) >> 16;
    return (unsigned short)u;
}
static __device__ __forceinline__ float bf2f(unsigned short h) {
    return __uint_as_float(((unsigned)h) << 16);
}
static __device__ __forceinline__ void split2(float x, unsigned short& hi, unsigned short& lo) {
    hi = f2bf(x);
    lo = f2bf(x - bf2f(hi));
}

// ---- async global->LDS staging, 128x32-short tile, 4-segment swizzle (r3-proven, 0 conflicts) ----
static __device__ __forceinline__ void stage_tile(unsigned short (*lds)[32],
                                                  const unsigned short* gbase,
                                                  int wave, int lane) {
#pragma unroll
    for (int c = 0; c < 2; c++) {
        int L = wave * 128 + c * 64 + lane;   // linear segment index 0..511
        int r = L >> 2, s = L & 3;
        int g = (s - (r >> 1)) & 3;
        __builtin_amdgcn_global_load_lds(
            (const __attribute__((address_space(1))) unsigned int*)(gbase + (size_t)r * EMBED + g * 8),
            (__attribute__((address_space(3))) unsigned int*)(&lds[r][s * 8]),
            16, 0, 0);
    }
}
static __device__ __forceinline__ bf16x8 read_frag(const unsigned short (*lds)[32], int r, int kq) {
    int s = ((kq >> 3) + (r >> 1)) & 3;
    return *(const bf16x8*)&lds[r][s * 8];
}

// ---------------- prep: wv_bar[i] = mean_d Wv[i][d] ----------------
__global__ void k_wvbar(const float* __restrict__ Wv, float* __restrict__ wvbar) {
    int r = blockIdx.x, t = threadIdx.x;
    float s = 0.f;
    for (int c = t; c < EMBED; c += 256) s += Wv[(size_t)r * EMBED + c];
    for (int d = 1; d < 64; d <<= 1) s += __shfl_xor(s, d);
    __shared__ float ws_[4];
    if ((t & 63) == 0) ws_[t >> 6] = s;
    __syncthreads();
    if (t == 0) wvbar[r] = (ws_[0] + ws_[1] + ws_[2] + ws_[3]) * (1.0f / EMBED);
}

// ---------------- prep: row split + vmean + cnt zeroing (fused, one X read) ----------------
__global__ __launch_bounds__(256) void k_xsplit_vmean(
    const float* __restrict__ X, const float* __restrict__ wvbar,
    unsigned short* __restrict__ Xhi, unsigned short* __restrict__ Xlo,
    float* __restrict__ vmean, int* __restrict__ cnt) {
    int row = blockIdx.x, t = threadIdx.x;
    float4 x4 = *(const float4*)(X + (size_t)row * EMBED + t * 4);
    float4 w4 = *(const float4*)(wvbar + t * 4);
    ushort4 h, l;
    split2(x4.x, h.x, l.x); split2(x4.y, h.y, l.y);
    split2(x4.z, h.z, l.z); split2(x4.w, h.w, l.w);
    *(ushort4*)(Xhi + (size_t)row * EMBED + t * 4) = h;
    *(ushort4*)(Xlo + (size_t)row * EMBED + t * 4) = l;
    float s = x4.x * w4.x + x4.y * w4.y + x4.z * w4.z + x4.w * w4.w;
    for (int d = 1; d < 64; d <<= 1) s += __shfl_xor(s, d);
    __shared__ float ws_[4];
    if ((t & 63) == 0) ws_[t >> 6] = s;
    __syncthreads();
    if (t == 0) { vmean[row] = ws_[0] + ws_[1] + ws_[2] + ws_[3]; cnt[row] = 0; }
}

// ---------------- split-bf16 GEMM: C[row][col] = sum_k A[row][k]*B[col][k] ----------------
__global__ __launch_bounds__(256) void k_gemm3(
    const unsigned short* __restrict__ Ahi, const unsigned short* __restrict__ Alo,
    const unsigned short* __restrict__ BThi, const unsigned short* __restrict__ BTlo,
    unsigned short* __restrict__ Chi, unsigned short* __restrict__ Clo) {
    __shared__ unsigned short Ah[128][32], Al[128][32], Bh[128][32], Bl[128][32];
    int bx = blockIdx.x;
    int bm = bx >> 3, bn = bx & 7;   // bn == XCD id under round-robin: B-tiles L2-local
    int tid = threadIdx.x, wave = tid >> 6, lane = tid & 63;
    int wm = (wave >> 1) * 64, wn = (wave & 1) * 64;
    int mrow = lane & 15, kq = (lane >> 4) * 8;

    f32x4 zero = {0.f, 0.f, 0.f, 0.f};
    f32x4 acc[4][4];
    for (int a = 0; a < 4; a++) for (int b = 0; b < 4; b++) acc[a][b] = zero;

    const unsigned short* Abase_h = Ahi + (size_t)(bm * 128) * EMBED;
    const unsigned short* Abase_l = Alo + (size_t)(bm * 128) * EMBED;
    const unsigned short* Bbase_h = BThi + (size_t)(bn * 128) * EMBED;
    const unsigned short* Bbase_l = BTlo + (size_t)(bn * 128) * EMBED;

    for (int k0 = 0; k0 < EMBED; k0 += 32) {
        __syncthreads();
        stage_tile(Ah, Abase_h + k0, wave, lane);
        stage_tile(Al, Abase_l + k0, wave, lane);
        stage_tile(Bh, Bbase_h + k0, wave, lane);
        stage_tile(Bl, Bbase_l + k0, wave, lane);
        __syncthreads();
        bf16x8 ah[4], al[4], bh[4], bl[4];
#pragma unroll
        for (int t = 0; t < 4; t++) {
            ah[t] = read_frag(Ah, wm + t * 16 + mrow, kq);
            al[t] = read_frag(Al, wm + t * 16 + mrow, kq);
            bh[t] = read_frag(Bh, wn + t * 16 + mrow, kq);
            bl[t] = read_frag(Bl, wn + t * 16 + mrow, kq);
        }
#pragma unroll
        for (int mt = 0; mt < 4; mt++)
#pragma unroll
            for (int nt = 0; nt < 4; nt++) {
                acc[mt][nt] = __builtin_amdgcn_mfma_f32_16x16x32_bf16(ah[mt], bh[nt], acc[mt][nt], 0, 0, 0);
                acc[mt][nt] = __builtin_amdgcn_mfma_f32_16x16x32_bf16(ah[mt], bl[nt], acc[mt][nt], 0, 0, 0);
                acc[mt][nt] = __builtin_amdgcn_mfma_f32_16x16x32_bf16(al[mt], bh[nt], acc[mt][nt], 0, 0, 0);
            }
    }
#pragma unroll
    for (int mt = 0; mt < 4; mt++)
#pragma unroll
        for (int nt = 0; nt < 4; nt++)
#pragma unroll
            for (int i = 0; i < 4; i++) {
                int row = bm * 128 + wm + mt * 16 + (lane >> 4) * 4 + i;
                int col = bn * 128 + wn + nt * 16 + (lane & 15);
                unsigned short h, l; split2(acc[mt][nt][i], h, l);
                Chi[(size_t)row * EMBED + col] = h;
                Clo[(size_t)row * EMBED + col] = l;
            }
}

// ---------------- scan: 128q x 128k block tile; each wave owns 32q x 128k ----------------
// r13/r14 post-mortem: pipeline variants were null (r13) or regressed via register blowup
// (r14: 164 arch + 128 acc = 292 -> 1 wave/SIMD, wall doubled). The binding constraint is
// register-capped occupancy: acc[4][8] = 128 VGPRs forced 2 waves/SIMD (212 total).
// Fix: halve the wave's q-extent -> acc[2][8] = 64 acc regs, total ~145 -> 3 waves/SIMD.
// The 128-key window per wave is PRESERVED (candidate/CAP statistics identical to the
// r3-r12-proven config). Block = 128q x 128k, 4 waves stacked in q sharing one K tile:
// staging drops to 4 loads/thread/step, LDS 16 KB. Simple 2-barrier loop (r13 proved
// dbuf gains nothing at this occupancy); no setprio (lockstep schedule, m190 null).
__global__ __launch_bounds__(256, 3) void k_scan(
    const unsigned short* __restrict__ Thi, const unsigned short* __restrict__ Xhi,
    int* __restrict__ cnt, int2* __restrict__ cand) {
    __shared__ unsigned short Th[128][32], Kh[128][32];
    // XCD-aware map: XCD = bid%8 under round-robin; each XCD owns 4 fixed 128-key tiles
    // per batch (1 MB hi-half working set -> L2-resident while qb sweeps).
    int bid = blockIdx.x;            // 0..4095
    int x   = bid & 7;               // XCD id
    int i   = bid >> 3;              // 0..511
    int kbi = i & 3;                 // which of this XCD's 4 key tiles
    int qb  = (i >> 2) & 31;         // 128-row q tile
    int b   = i >> 7;                // batch
    int kb  = x * 4 + kbi;           // 0..31
    int tid = threadIdx.x, wave = tid >> 6, lane = tid & 63;
    int wq = wave * 32;              // q offset of this wave (4 waves stacked in q)
    int mrow = lane & 15, kq = (lane >> 4) * 8;
    size_t qrow0 = (size_t)b * SEQ + (size_t)qb * 128;
    size_t krow0 = (size_t)b * SEQ + (size_t)kb * 128;

    const unsigned short* Tbase = Thi + qrow0 * EMBED;
    const unsigned short* Xbase = Xhi + krow0 * EMBED;

    f32x4 zero = {0.f, 0.f, 0.f, 0.f};
    f32x4 acc[2][8];
    for (int a = 0; a < 2; a++) for (int c = 0; c < 8; c++) acc[a][c] = zero;

    for (int k0 = 0; k0 < EMBED; k0 += 32) {
        __syncthreads();
        stage_tile(Th, Tbase + k0, wave, lane);
        stage_tile(Kh, Xbase + k0, wave, lane);
        __syncthreads();
        bf16x8 ah[2];
#pragma unroll
        for (int mt = 0; mt < 2; mt++)
            ah[mt] = read_frag(Th, wq + mt * 16 + mrow, kq);
#pragma unroll
        for (int nt = 0; nt < 8; nt++) {
            bf16x8 bh = read_frag(Kh, nt * 16 + mrow, kq);
#pragma unroll
            for (int mt = 0; mt < 2; mt++)
                acc[mt][nt] = __builtin_amdgcn_mfma_f32_16x16x32_bf16(ah[mt], bh, acc[mt][nt], 0, 0, 0);
        }
    }

    // ---- epilogue: per-row max over this wave's 128 keys (intra-wave; no LDS, no barrier) ----
#pragma unroll
    for (int mt = 0; mt < 2; mt++)
#pragma unroll
        for (int i2 = 0; i2 < 4; i2++) {
            float v = -INFINITY;
#pragma unroll
            for (int nt = 0; nt < 8; nt++) v = fmaxf(v, acc[mt][nt][i2]);
#pragma unroll
            for (int d = 1; d < 16; d <<= 1) v = fmaxf(v, __shfl_xor(v, d));
            float th = v - TSCAN_U;
            int grow = (int)qrow0 + wq + mt * 16 + (lane >> 4) * 4 + i2;
#pragma unroll
            for (int nt = 0; nt < 8; nt++) {
                float s = acc[mt][nt][i2];
                if (s >= th) {
                    int gcol = (int)krow0 + nt * 16 + (lane & 15);
                    int idx = atomicAdd(&cnt[grow], 1);
                    if (idx < CAP)
                        cand[(size_t)grow * CAP + idx] = make_int2(gcol, __float_as_int(s * 0.03125f));
                }
            }
        }
}

// ---------------- rescore: 4 rows per block, one wave per row, barrier-free ----------------
__global__ __launch_bounds__(256) void k_rescore(
    const unsigned short* __restrict__ Thi, const unsigned short* __restrict__ Tlo,
    const float* __restrict__ X, const float* __restrict__ vmean,
    const int* __restrict__ cnt, const int2* __restrict__ cand,
    float* __restrict__ out) {
    int wave = threadIdx.x >> 6, lane = threadIdx.x & 63;
    int row = blockIdx.x * 4 + wave;
    int c = cnt[row]; if (c > CAP) c = CAP;
    const int2* cl = cand + (size_t)row * CAP;

    float smax = -INFINITY;
    for (int j = lane; j < c; j += 64) smax = fmaxf(smax, __int_as_float(cl[j].y));
    for (int d = 1; d < 64; d <<= 1) smax = fmaxf(smax, __shfl_xor(smax, d));
    float th = smax - TRES;

    float q[16];
    {
        const unsigned short* qh = Thi + (size_t)row * EMBED + lane * 16;
        const unsigned short* ql = Tlo + (size_t)row * EMBED + lane * 16;
        bf16x8 h0 = *(const bf16x8*)qh, h1 = *(const bf16x8*)(qh + 8);
        bf16x8 l0 = *(const bf16x8*)ql, l1 = *(const bf16x8*)(ql + 8);
#pragma unroll
        for (int i = 0; i < 8; i++) {
            q[i]     = bf2f((unsigned short)h0[i]) + bf2f((unsigned short)l0[i]);
            q[i + 8] = bf2f((unsigned short)h1[i]) + bf2f((unsigned short)l1[i]);
        }
    }

    __shared__ int   sm_[4][CAP];
    __shared__ float sl_[4][CAP];
    __shared__ int   ns_[4];
    if (lane == 0) ns_[wave] = 0;
    for (int j = lane; j < c; j += 64) {
        int2 p = cl[j];
        if (__int_as_float(p.y) >= th) {
            int idx = atomicAdd(&ns_[wave], 1);
            sm_[wave][idx] = p.x;
        }
    }
    int ns = ns_[wave];
    for (int t = 0; t < ns; t++) {
        int m = sm_[wave][t];
        const float* xr = X + (size_t)m * EMBED + lane * 16;
        float4 a0 = *(const float4*)(xr);
        float4 a1 = *(const float4*)(xr + 4);
        float4 a2 = *(const float4*)(xr + 8);
        float4 a3 = *(const float4*)(xr + 12);
        float dp = q[0]*a0.x + q[1]*a0.y + q[2]*a0.z + q[3]*a0.w
                 + q[4]*a1.x + q[5]*a1.y + q[6]*a1.z + q[7]*a1.w
                 + q[8]*a2.x + q[9]*a2.y + q[10]*a2.z + q[11]*a2.w
                 + q[12]*a3.x + q[13]*a3.y + q[14]*a3.z + q[15]*a3.w;
        for (int d = 1; d < 64; d <<= 1) dp += __shfl_xor(dp, d);
        if (lane == 0) sl_[wave][t] = dp * 0.03125f;
    }
    if (lane == 0) {
        float lm = -INFINITY;
        for (int t = 0; t < ns; t++) lm = fmaxf(lm, sl_[wave][t]);
        float den = 0.f, num = 0.f;
        for (int t = 0; t < ns; t++) {
            float e = __expf(sl_[wave][t] - lm);
            den += e;
            num += e * vmean[sm_[wave][t]];
        }
        out[row] = num / den;
    }
}

extern "C" void kernel_launch(void* const* d_in, const int* in_sizes, int n_in,
                              void* d_out, int out_size, void* d_ws, size_t ws_size,
                              hipStream_t stream) {
    const float* X  = (const float*)d_in[0];
    const float* Wq = (const float*)d_in[1];
    const float* Wk = (const float*)d_in[2];
    const float* Wv = (const float*)d_in[3];
    float* out = (float*)d_out;

    char* p = (char*)d_ws;
    auto alloc = [&](size_t bytes) -> void* {
        void* q = (void*)p;
        p += (bytes + 255) & ~(size_t)255;
        return q;
    };
    unsigned short* Wqhi = (unsigned short*)alloc((size_t)EMBED * EMBED * 2);
    unsigned short* Wqlo = (unsigned short*)alloc((size_t)EMBED * EMBED * 2);
    unsigned short* Wkhi = (unsigned short*)alloc((size_t)EMBED * EMBED * 2);
    unsigned short* Wklo = (unsigned short*)alloc((size_t)EMBED * EMBED * 2);
    unsigned short* MThi = (unsigned short*)alloc((size_t)EMBED * EMBED * 2);
    unsigned short* MTlo = (unsigned short*)alloc((size_t)EMBED * EMBED * 2);
    unsigned short* Xhi  = (unsigned short*)alloc((size_t)ROWS * EMBED * 2);
    unsigned short* Xlo  = (unsigned short*)alloc((size_t)ROWS * EMBED * 2);
    unsigned short* Thi  = (unsigned short*)alloc((size_t)ROWS * EMBED * 2);
    unsigned short* Tlo  = (unsigned short*)alloc((size_t)ROWS * EMBED * 2);
    float* wvbar = (float*)alloc(EMBED * 4);
    float* vmean = (float*)alloc((size_t)ROWS * 4);
    int*   cnt   = (int*)alloc((size_t)ROWS * 4);
    int2*  cand  = (int2*)alloc((size_t)ROWS * CAP * 8);

    k_wvbar<<<EMBED, 256, 0, stream>>>(Wv, wvbar);
    // Row splits of the ORIGINAL Wq/Wk (M contraction is over the contiguous output dim).
    // vmean/cnt args are scratch here (rows 0..1023; real run below overwrites all rows).
    k_xsplit_vmean<<<EMBED, 256, 0, stream>>>(Wq, wvbar, Wqhi, Wqlo, vmean, cnt);
    k_xsplit_vmean<<<EMBED, 256, 0, stream>>>(Wk, wvbar, Wkhi, Wklo, vmean, cnt);
    // M^T[b][a] = sum_n Wk[b][n]*Wq[a][n]
    k_gemm3<<<64, 256, 0, stream>>>(Wkhi, Wklo, Wqhi, Wqlo, MThi, MTlo);
    k_xsplit_vmean<<<ROWS, 256, 0, stream>>>(X, wvbar, Xhi, Xlo, vmean, cnt);  // real vmean + cnt=0
    k_gemm3<<<1024, 256, 0, stream>>>(Xhi, Xlo, MThi, MTlo, Thi, Tlo);         // T = X.M
    k_scan<<<4096, 256, 0, stream>>>(Thi, Xhi, cnt, cand);
    k_rescore<<<ROWS / 4, 256, 0, stream>>>(Thi, Tlo, X, vmean, cnt, cand, out);
}

// Round 4
// 485.588 us; speedup vs baseline: 1.4219x; 1.0424x over previous
//
#include <hip/hip_runtime.h>

#define EMBED 1024
#define BATCH 4
#define SEQ   4096
#define ROWS  (BATCH*SEQ)   // 16384
#define CAP   128           // candidate slots per row (r3-r12 proven)
#define TSCAN_U 1600.0f     // scan margin, unscaled (50 scaled) — r12-proven passing
#define TRES  75.0f         // rescore margin, scaled logits (proven)

typedef __attribute__((ext_vector_type(8))) short bf16x8;
typedef __attribute__((ext_vector_type(4))) float f32x4;

static __device__ __forceinline__ unsigned short f2bf(float x) {
    unsigned u = __float_as_uint(x);
    u = (u + 0x7fffu + ((u >> 16) & 1u)) >> 16;
    return (unsigned short)u;
}
static __device__ __forceinline__ float bf2f(unsigned short h) {
    return __uint_as_float(((unsigned)h) << 16);
}
static __device__ __forceinline__ void split2(float x, unsigned short& hi, unsigned short& lo) {
    hi = f2bf(x);
    lo = f2bf(x - bf2f(hi));
}

// ---- async global->LDS staging, 128x32-short tile, 4-segment swizzle (r3-proven, 0 conflicts) ----
static __device__ __forceinline__ void stage_tile(unsigned short (*lds)[32],
                                                  const unsigned short* gbase,
                                                  int wave, int lane) {
#pragma unroll
    for (int c = 0; c < 2; c++) {
        int L = wave * 128 + c * 64 + lane;   // linear segment index 0..511
        int r = L >> 2, s = L & 3;
        int g = (s - (r >> 1)) & 3;
        __builtin_amdgcn_global_load_lds(
            (const __attribute__((address_space(1))) unsigned int*)(gbase + (size_t)r * EMBED + g * 8),
            (__attribute__((address_space(3))) unsigned int*)(&lds[r][s * 8]),
            16, 0, 0);
    }
}
static __device__ __forceinline__ bf16x8 read_frag(const unsigned short (*lds)[32], int r, int kq) {
    int s = ((kq >> 3) + (r >> 1)) & 3;
    return *(const bf16x8*)&lds[r][s * 8];
}

// ---------------- prep: wv_bar[i] = mean_d Wv[i][d] ----------------
__global__ void k_wvbar(const float* __restrict__ Wv, float* __restrict__ wvbar) {
    int r = blockIdx.x, t = threadIdx.x;
    float s = 0.f;
    for (int c = t; c < EMBED; c += 256) s += Wv[(size_t)r * EMBED + c];
    for (int d = 1; d < 64; d <<= 1) s += __shfl_xor(s, d);
    __shared__ float ws_[4];
    if ((t & 63) == 0) ws_[t >> 6] = s;
    __syncthreads();
    if (t == 0) wvbar[r] = (ws_[0] + ws_[1] + ws_[2] + ws_[3]) * (1.0f / EMBED);
}

// ---------------- prep: row split + vmean + cnt zeroing (fused, one X read) ----------------
__global__ __launch_bounds__(256) void k_xsplit_vmean(
    const float* __restrict__ X, const float* __restrict__ wvbar,
    unsigned short* __restrict__ Xhi, unsigned short* __restrict__ Xlo,
    float* __restrict__ vmean, int* __restrict__ cnt) {
    int row = blockIdx.x, t = threadIdx.x;
    float4 x4 = *(const float4*)(X + (size_t)row * EMBED + t * 4);
    float4 w4 = *(const float4*)(wvbar + t * 4);
    ushort4 h, l;
    split2(x4.x, h.x, l.x); split2(x4.y, h.y, l.y);
    split2(x4.z, h.z, l.z); split2(x4.w, h.w, l.w);
    *(ushort4*)(Xhi + (size_t)row * EMBED + t * 4) = h;
    *(ushort4*)(Xlo + (size_t)row * EMBED + t * 4) = l;
    float s = x4.x * w4.x + x4.y * w4.y + x4.z * w4.z + x4.w * w4.w;
    for (int d = 1; d < 64; d <<= 1) s += __shfl_xor(s, d);
    __shared__ float ws_[4];
    if ((t & 63) == 0) ws_[t >> 6] = s;
    __syncthreads();
    if (t == 0) { vmean[row] = ws_[0] + ws_[1] + ws_[2] + ws_[3]; cnt[row] = 0; }
}

// ---------------- split-bf16 GEMM: C[row][col] = sum_k A[row][k]*B[col][k] ----------------
__global__ __launch_bounds__(256) void k_gemm3(
    const unsigned short* __restrict__ Ahi, const unsigned short* __restrict__ Alo,
    const unsigned short* __restrict__ BThi, const unsigned short* __restrict__ BTlo,
    unsigned short* __restrict__ Chi, unsigned short* __restrict__ Clo) {
    __shared__ unsigned short Ah[128][32], Al[128][32], Bh[128][32], Bl[128][32];
    int bx = blockIdx.x;
    int bm = bx >> 3, bn = bx & 7;   // bn == XCD id under round-robin: B-tiles L2-local
    int tid = threadIdx.x, wave = tid >> 6, lane = tid & 63;
    int wm = (wave >> 1) * 64, wn = (wave & 1) * 64;
    int mrow = lane & 15, kq = (lane >> 4) * 8;

    f32x4 zero = {0.f, 0.f, 0.f, 0.f};
    f32x4 acc[4][4];
    for (int a = 0; a < 4; a++) for (int b = 0; b < 4; b++) acc[a][b] = zero;

    const unsigned short* Abase_h = Ahi + (size_t)(bm * 128) * EMBED;
    const unsigned short* Abase_l = Alo + (size_t)(bm * 128) * EMBED;
    const unsigned short* Bbase_h = BThi + (size_t)(bn * 128) * EMBED;
    const unsigned short* Bbase_l = BTlo + (size_t)(bn * 128) * EMBED;

    for (int k0 = 0; k0 < EMBED; k0 += 32) {
        __syncthreads();
        stage_tile(Ah, Abase_h + k0, wave, lane);
        stage_tile(Al, Abase_l + k0, wave, lane);
        stage_tile(Bh, Bbase_h + k0, wave, lane);
        stage_tile(Bl, Bbase_l + k0, wave, lane);
        __syncthreads();
        bf16x8 ah[4], al[4], bh[4], bl[4];
#pragma unroll
        for (int t = 0; t < 4; t++) {
            ah[t] = read_frag(Ah, wm + t * 16 + mrow, kq);
            al[t] = read_frag(Al, wm + t * 16 + mrow, kq);
            bh[t] = read_frag(Bh, wn + t * 16 + mrow, kq);
            bl[t] = read_frag(Bl, wn + t * 16 + mrow, kq);
        }
#pragma unroll
        for (int mt = 0; mt < 4; mt++)
#pragma unroll
            for (int nt = 0; nt < 4; nt++) {
                acc[mt][nt] = __builtin_amdgcn_mfma_f32_16x16x32_bf16(ah[mt], bh[nt], acc[mt][nt], 0, 0, 0);
                acc[mt][nt] = __builtin_amdgcn_mfma_f32_16x16x32_bf16(ah[mt], bl[nt], acc[mt][nt], 0, 0, 0);
                acc[mt][nt] = __builtin_amdgcn_mfma_f32_16x16x32_bf16(al[mt], bh[nt], acc[mt][nt], 0, 0, 0);
            }
    }
#pragma unroll
    for (int mt = 0; mt < 4; mt++)
#pragma unroll
        for (int nt = 0; nt < 4; nt++)
#pragma unroll
            for (int i = 0; i < 4; i++) {
                int row = bm * 128 + wm + mt * 16 + (lane >> 4) * 4 + i;
                int col = bn * 128 + wn + nt * 16 + (lane & 15);
                unsigned short h, l; split2(acc[mt][nt][i], h, l);
                Chi[(size_t)row * EMBED + col] = h;
                Clo[(size_t)row * EMBED + col] = l;
            }
}

// ---------------- scan: 128q x 128k block tile; each wave owns 64q x 64k ----------------
// r13-r15 post-mortem ledger: dbuf-drain0 null (r13); 3-buf counted-vmcnt regressed via
// VGPR blowup (r14); occupancy 28->41% bought only -4% (r15) => latency/overhead-bound,
// all pipes <50%. Two levers left inside the 2-barrier template, both applied here:
//  (1) wave tile 32x128 -> 64x64: FLOP per LDS-read-byte 25.6 -> 32 (8 ds_read_b128 per
//      16 MFMA instead of 10/16), SAME 64 acc VGPRs as r15.
//  (2) BK=64: two K=32 sub-steps per barrier interval (two statically-named buffer pairs,
//      zero new layout code). Barrier intervals 32 -> 16; vmcnt-drain + first-read latency
//      amortized 2x. LDS 33 KB -> still 3 blocks/CU (reg-capped).
// Candidate semantics PRESERVED: per-row threshold max is exchanged across the two
// k-half waves via LDS, so the window is the block's full 128 keys — identical statistics
// to the r3-r12-proven 128-key window.
static __device__ __forceinline__ void scan_half(
    const unsigned short (*Th_)[32], const unsigned short (*Kh_)[32],
    int wq, int wk, int mrow, int kq, f32x4 (&acc)[4][4]) {
    bf16x8 ah[4], bh[4];
#pragma unroll
    for (int t = 0; t < 4; t++) {
        ah[t] = read_frag(Th_, wq + t * 16 + mrow, kq);
        bh[t] = read_frag(Kh_, wk + t * 16 + mrow, kq);
    }
#pragma unroll
    for (int mt = 0; mt < 4; mt++)
#pragma unroll
        for (int nt = 0; nt < 4; nt++)
            acc[mt][nt] = __builtin_amdgcn_mfma_f32_16x16x32_bf16(ah[mt], bh[nt], acc[mt][nt], 0, 0, 0);
}

__global__ __launch_bounds__(256, 3) void k_scan(
    const unsigned short* __restrict__ Thi, const unsigned short* __restrict__ Xhi,
    int* __restrict__ cnt, int2* __restrict__ cand) {
    __shared__ unsigned short ThA[128][32], KhA[128][32];
    __shared__ unsigned short ThB[128][32], KhB[128][32];   // BK=64 as two K=32 halves
    __shared__ float rowmax_[2][2][64];                     // [wc][wr][local row]
    // XCD-aware map: XCD = bid%8 under round-robin; each XCD owns 4 fixed 128-key tiles
    // per batch (1 MB hi-half working set -> L2-resident while qb sweeps).
    int bid = blockIdx.x;            // 0..4095
    int x   = bid & 7;               // XCD id
    int i   = bid >> 3;              // 0..511
    int kbi = i & 3;                 // which of this XCD's 4 key tiles
    int qb  = (i >> 2) & 31;         // 128-row q tile
    int b   = i >> 7;                // batch
    int kb  = x * 4 + kbi;           // 0..31
    int tid = threadIdx.x, wave = tid >> 6, lane = tid & 63;
    int wr = wave >> 1, wc = wave & 1;
    int wq = wr * 64;                // q offset of this wave
    int wk = wc * 64;                // k offset of this wave
    int mrow = lane & 15, kq = (lane >> 4) * 8;
    size_t qrow0 = (size_t)b * SEQ + (size_t)qb * 128;
    size_t krow0 = (size_t)b * SEQ + (size_t)kb * 128;

    const unsigned short* Tbase = Thi + qrow0 * EMBED;
    const unsigned short* Xbase = Xhi + krow0 * EMBED;

    f32x4 zero = {0.f, 0.f, 0.f, 0.f};
    f32x4 acc[4][4];
    for (int a = 0; a < 4; a++) for (int c = 0; c < 4; c++) acc[a][c] = zero;

    for (int k0 = 0; k0 < EMBED; k0 += 64) {
        __syncthreads();
        stage_tile(ThA, Tbase + k0,      wave, lane);
        stage_tile(KhA, Xbase + k0,      wave, lane);
        stage_tile(ThB, Tbase + k0 + 32, wave, lane);
        stage_tile(KhB, Xbase + k0 + 32, wave, lane);
        __syncthreads();
        scan_half(ThA, KhA, wq, wk, mrow, kq, acc);
        scan_half(ThB, KhB, wq, wk, mrow, kq, acc);
    }

    // ---- epilogue pass 1: per-row max over this wave's 64 keys -> LDS exchange ----
#pragma unroll
    for (int mt = 0; mt < 4; mt++)
#pragma unroll
        for (int i2 = 0; i2 < 4; i2++) {
            float v = -INFINITY;
#pragma unroll
            for (int nt = 0; nt < 4; nt++) v = fmaxf(v, acc[mt][nt][i2]);
#pragma unroll
            for (int d = 1; d < 16; d <<= 1) v = fmaxf(v, __shfl_xor(v, d));
            if ((lane & 15) == 0) {
                int lr = mt * 16 + (lane >> 4) * 4 + i2;
                rowmax_[wc][wr][lr] = v;
            }
        }
    __syncthreads();
    // ---- epilogue pass 2: threshold over the block's FULL 128 keys; emit candidates ----
#pragma unroll
    for (int mt = 0; mt < 4; mt++)
#pragma unroll
        for (int i2 = 0; i2 < 4; i2++) {
            int lr = mt * 16 + (lane >> 4) * 4 + i2;
            float th = fmaxf(rowmax_[0][wr][lr], rowmax_[1][wr][lr]) - TSCAN_U;
            int grow = (int)qrow0 + wq + lr;
#pragma unroll
            for (int nt = 0; nt < 4; nt++) {
                float s = acc[mt][nt][i2];
                if (s >= th) {
                    int gcol = (int)krow0 + wk + nt * 16 + (lane & 15);
                    int idx = atomicAdd(&cnt[grow], 1);
                    if (idx < CAP)
                        cand[(size_t)grow * CAP + idx] = make_int2(gcol, __float_as_int(s * 0.03125f));
                }
            }
        }
}

// ---------------- rescore: 4 rows per block, one wave per row, barrier-free ----------------
__global__ __launch_bounds__(256) void k_rescore(
    const unsigned short* __restrict__ Thi, const unsigned short* __restrict__ Tlo,
    const float* __restrict__ X, const float* __restrict__ vmean,
    const int* __restrict__ cnt, const int2* __restrict__ cand,
    float* __restrict__ out) {
    int wave = threadIdx.x >> 6, lane = threadIdx.x & 63;
    int row = blockIdx.x * 4 + wave;
    int c = cnt[row]; if (c > CAP) c = CAP;
    const int2* cl = cand + (size_t)row * CAP;

    float smax = -INFINITY;
    for (int j = lane; j < c; j += 64) smax = fmaxf(smax, __int_as_float(cl[j].y));
    for (int d = 1; d < 64; d <<= 1) smax = fmaxf(smax, __shfl_xor(smax, d));
    float th = smax - TRES;

    float q[16];
    {
        const unsigned short* qh = Thi + (size_t)row * EMBED + lane * 16;
        const unsigned short* ql = Tlo + (size_t)row * EMBED + lane * 16;
        bf16x8 h0 = *(const bf16x8*)qh, h1 = *(const bf16x8*)(qh + 8);
        bf16x8 l0 = *(const bf16x8*)ql, l1 = *(const bf16x8*)(ql + 8);
#pragma unroll
        for (int i = 0; i < 8; i++) {
            q[i]     = bf2f((unsigned short)h0[i]) + bf2f((unsigned short)l0[i]);
            q[i + 8] = bf2f((unsigned short)h1[i]) + bf2f((unsigned short)l1[i]);
        }
    }

    __shared__ int   sm_[4][CAP];
    __shared__ float sl_[4][CAP];
    __shared__ int   ns_[4];
    if (lane == 0) ns_[wave] = 0;
    for (int j = lane; j < c; j += 64) {
        int2 p = cl[j];
        if (__int_as_float(p.y) >= th) {
            int idx = atomicAdd(&ns_[wave], 1);
            sm_[wave][idx] = p.x;
        }
    }
    int ns = ns_[wave];
    for (int t = 0; t < ns; t++) {
        int m = sm_[wave][t];
        const float* xr = X + (size_t)m * EMBED + lane * 16;
        float4 a0 = *(const float4*)(xr);
        float4 a1 = *(const float4*)(xr + 4);
        float4 a2 = *(const float4*)(xr + 8);
        float4 a3 = *(const float4*)(xr + 12);
        float dp = q[0]*a0.x + q[1]*a0.y + q[2]*a0.z + q[3]*a0.w
                 + q[4]*a1.x + q[5]*a1.y + q[6]*a1.z + q[7]*a1.w
                 + q[8]*a2.x + q[9]*a2.y + q[10]*a2.z + q[11]*a2.w
                 + q[12]*a3.x + q[13]*a3.y + q[14]*a3.z + q[15]*a3.w;
        for (int d = 1; d < 64; d <<= 1) dp += __shfl_xor(dp, d);
        if (lane == 0) sl_[wave][t] = dp * 0.03125f;
    }
    if (lane == 0) {
        float lm = -INFINITY;
        for (int t = 0; t < ns; t++) lm = fmaxf(lm, sl_[wave][t]);
        float den = 0.f, num = 0.f;
        for (int t = 0; t < ns; t++) {
            float e = __expf(sl_[wave][t] - lm);
            den += e;
            num += e * vmean[sm_[wave][t]];
        }
        out[row] = num / den;
    }
}

extern "C" void kernel_launch(void* const* d_in, const int* in_sizes, int n_in,
                              void* d_out, int out_size, void* d_ws, size_t ws_size,
                              hipStream_t stream) {
    const float* X  = (const float*)d_in[0];
    const float* Wq = (const float*)d_in[1];
    const float* Wk = (const float*)d_in[2];
    const float* Wv = (const float*)d_in[3];
    float* out = (float*)d_out;

    char* p = (char*)d_ws;
    auto alloc = [&](size_t bytes) -> void* {
        void* q = (void*)p;
        p += (bytes + 255) & ~(size_t)255;
        return q;
    };
    unsigned short* Wqhi = (unsigned short*)alloc((size_t)EMBED * EMBED * 2);
    unsigned short* Wqlo = (unsigned short*)alloc((size_t)EMBED * EMBED * 2);
    unsigned short* Wkhi = (unsigned short*)alloc((size_t)EMBED * EMBED * 2);
    unsigned short* Wklo = (unsigned short*)alloc((size_t)EMBED * EMBED * 2);
    unsigned short* MThi = (unsigned short*)alloc((size_t)EMBED * EMBED * 2);
    unsigned short* MTlo = (unsigned short*)alloc((size_t)EMBED * EMBED * 2);
    unsigned short* Xhi  = (unsigned short*)alloc((size_t)ROWS * EMBED * 2);
    unsigned short* Xlo  = (unsigned short*)alloc((size_t)ROWS * EMBED * 2);
    unsigned short* Thi  = (unsigned short*)alloc((size_t)ROWS * EMBED * 2);
    unsigned short* Tlo  = (unsigned short*)alloc((size_t)ROWS * EMBED * 2);
    float* wvbar = (float*)alloc(EMBED * 4);
    float* vmean = (float*)alloc((size_t)ROWS * 4);
    int*   cnt   = (int*)alloc((size_t)ROWS * 4);
    int2*  cand  = (int2*)alloc((size_t)ROWS * CAP * 8);

    k_wvbar<<<EMBED, 256, 0, stream>>>(Wv, wvbar);
    // Row splits of the ORIGINAL Wq/Wk (M contraction is over the contiguous output dim).
    // vmean/cnt args are scratch here (rows 0..1023; real run below overwrites all rows).
    k_xsplit_vmean<<<EMBED, 256, 0, stream>>>(Wq, wvbar, Wqhi, Wqlo, vmean, cnt);
    k_xsplit_vmean<<<EMBED, 256, 0, stream>>>(Wk, wvbar, Wkhi, Wklo, vmean, cnt);
    // M^T[b][a] = sum_n Wk[b][n]*Wq[a][n]
    k_gemm3<<<64, 256, 0, stream>>>(Wkhi, Wklo, Wqhi, Wqlo, MThi, MTlo);
    k_xsplit_vmean<<<ROWS, 256, 0, stream>>>(X, wvbar, Xhi, Xlo, vmean, cnt);  // real vmean + cnt=0
    k_gemm3<<<1024, 256, 0, stream>>>(Xhi, Xlo, MThi, MTlo, Thi, Tlo);         // T = X.M
    k_scan<<<4096, 256, 0, stream>>>(Thi, Xhi, cnt, cand);
    k_rescore<<<ROWS / 4, 256, 0, stream>>>(Thi, Tlo, X, vmean, cnt, cand, out);
}